// Round 16
// baseline (1469.892 us; speedup 1.0000x reference)
//
#include <hip/hip_runtime.h>

// HBMA fused: full-search block matching (16x16 blocks, +/-4 search) + predicted
// frame gather. N=8, C=3, H=W=1024.
//
// R16 = R8 (best verified, 230us kernel) with the reduce/argmin tail moved off
// the LDS pipe. R15's DCE-proof ablation measured compute-only = ~182us of the
// 230 -> LDS pipe (~400 wave-instrs: 264 ds_read + 108 shfl + publish) and
// VALU (~69us) are co-bottlenecks. Changes vs R8 (both HW-validated in R13,
// which passed absmax 0 -- its slowness was descriptor spilling, not these):
//  * 16-lane column reduce via DPP row_ror adds (VALU pipe): -108 LDS-pipe
//    ops per wave.
//  * register-only argmin: in-lane scan of the lane's 27 (ascending disp
//    index, strict <), then cross-group min via xor-16/32 only (post-DPP all
//    16 lanes of a row hold identical sums, so xor 1..8 are no-ops) with
//    lowest-index-wins == jax scan tie-break. Removes costL publish/reads +
//    the lgkmcnt serialization.
// Everything else (staging, SAD, gather, launch config) byte-identical to R8.
// OOB ref chunks load a zeroed 16B block (MV region, zeroed each launch).

namespace {
constexpr int BLKi  = 16;
constexpr int NSDi  = 4;
constexpr int ND    = 9;
constexpr int Nn    = 8;
constexpr int Cc    = 3;
constexpr int Hh    = 1024;
constexpr int Ww    = 1024;
constexpr int BHn   = 64;
constexpr int STRIPW = 64;                    // 4 blocks per wg, side by side
constexpr int SW    = 72;                     // strip width  (64 + 8)
constexpr int SH    = 24;                     // strip height (16 + 8)
constexpr int STRIP_FLOATS = Cc * SH * SW;    // 5184
constexpr int STRIP_CHUNKS = STRIP_FLOATS/4;  // 1296 (18/row: chunks never straddle)
constexpr int TGT_FLOATS   = Cc * BLKi * STRIPW; // 3072
constexpr int TOT_CHUNKS   = STRIP_CHUNKS + TGT_FLOATS / 4; // 2064
constexpr int ITERS        = 9;               // ceil(2064/256)
constexpr int LDSF         = ITERS * 256 * 4; // 9216 floats (incl. pad)
constexpr int MV_SIZE = Nn * 2 * BHn * BHn;   // 65536
constexpr int NWG     = Nn * BHn * (Ww / STRIPW); // 8192
}

typedef const __attribute__((address_space(1))) void* gas_ptr;
typedef __attribute__((address_space(3))) void*       las_ptr;

__global__ void init_kernel(float* __restrict__ out) {
    int i = blockIdx.x * 256 + threadIdx.x;
    if (i < MV_SIZE) out[i] = 0.0f;   // MV output = zeros; doubles as zero-source
}

// x += row_ror<CTRL>(x): DPP rotate within the 16-lane row; VALU pipe only.
// (validated on HW in R13: absmax 0)
template<int CTRL>
__device__ __forceinline__ float dpp_ror_add(float x) {
    int r = __builtin_amdgcn_update_dpp(__float_as_int(x), __float_as_int(x),
                                        CTRL, 0xf, 0xf, false);
    return x + __int_as_float(r);
}

__global__ __launch_bounds__(256, 2) void hbma_kernel(
        const float* __restrict__ ref,
        const float* __restrict__ tgt,
        float* __restrict__ pred,
        const float* __restrict__ zsrc) {
    __shared__ float ldsA[LDSF];               // [strip 5184][target 3072][pad]

    const int tid  = (int)threadIdx.x;
    const int wid  = tid >> 6;                 // wave = which of 4 blocks
    const int lane = tid & 63;
    const int w    = (int)blockIdx.x;          // 0..8191
    const int n    = w >> 10;                  // 1024 wg per image
    const int rem  = w & 1023;
    const int Y0   = (rem >> 4) * BLKi;        // block row * 16
    const int X0   = (rem & 15) * STRIPW;      // strip origin
    const float* refn  = ref  + (size_t)n * Cc * Hh * Ww;
    const float* tgtn  = tgt  + (size_t)n * Cc * Hh * Ww;
    float*       predn = pred + (size_t)n * Cc * Hh * Ww;

    // ---- cooperative staging: strip (zero-padded) then target, 16B chunks ----
    #pragma unroll
    for (int i = 0; i < ITERS; ++i) {
        const int ck = i * 256 + tid;          // chunk id
        if (ck < TOT_CHUNKS) {
            const float* src;
            if (ck < STRIP_CHUNKS) {
                const int c    = ck / (SH * SW / 4);           // /432
                const int rm   = ck - c * (SH * SW / 4);
                const int r    = rm / (SW / 4);                // /18
                const int colc = (rm - r * (SW / 4)) * 4;
                const int gy   = Y0 - NSDi + r;
                const int gx   = X0 - NSDi + colc;             // mult of 4: no straddle
                const bool ok  = ((unsigned)gy < (unsigned)Hh) &&
                                 ((unsigned)gx < (unsigned)Ww);
                src = ok ? (refn + (c << 20) + (gy << 10) + gx) : zsrc;
            } else {
                const int tk   = ck - STRIP_CHUNKS;
                const int c    = tk >> 8;                      // 256 chunks/channel
                const int rm2  = tk & 255;
                const int y    = rm2 >> 4;
                const int colc = (rm2 & 15) * 4;
                src = tgtn + (c << 20) + ((Y0 + y) << 10) + X0 + colc;
            }
            // LDS dest: wave-uniform base; HW adds lane*16B
            __builtin_amdgcn_global_load_lds((gas_ptr)src,
                    (las_ptr)(ldsA + i * 1024 + (tid & 192) * 4), 16, 0, 0);
        }
    }
    __syncthreads();                           // the ONLY barrier

    // ---- SAD: this wave's block, lane = col(16) x dx-group(4) ----
    const int col  = lane & 15;
    const int g    = lane >> 4;
    const int d0   = g * 3;                    // 0,3,6 (9 = idle group, harmless)
    const int colS = (wid << 4) + col;         // column within strip
    const float* __restrict__ ldsT = ldsA + STRIP_FLOATS;

    float acc[ND][3];
    #pragma unroll
    for (int j = 0; j < ND; ++j) {
        acc[j][0] = 0.0f; acc[j][1] = 0.0f; acc[j][2] = 0.0f;
    }

    #pragma unroll 1
    for (int c = 0; c < Cc; ++c) {
        float T[BLKi];
        #pragma unroll
        for (int y = 0; y < BLKi; ++y)
            T[y] = ldsT[(c * BLKi + y) * STRIPW + colS];

        #pragma unroll
        for (int r = 0; r < SH; ++r) {
            const float* rp = ldsA + (c * SH + r) * SW + colS + d0;
            const float rv0 = rp[0], rv1 = rp[1], rv2 = rp[2];
            #pragma unroll
            for (int j = 0; j < ND; ++j) {
                const int y = r - j;           // compile-time after unroll
                if (y >= 0 && y < BLKi) {
                    const float tv = T[y];
                    acc[j][0] += fabsf(rv0 - tv);
                    acc[j][1] += fabsf(rv1 - tv);
                    acc[j][2] += fabsf(rv2 - tv);
                }
            }
        }
    }

    // ---- 16-lane column reduce on the VALU pipe (DPP row rotations) ----
    #pragma unroll
    for (int j = 0; j < ND; ++j) {
        #pragma unroll
        for (int dd = 0; dd < 3; ++dd) {
            float v = acc[j][dd];
            v = dpp_ror_add<0x128>(v);         // row_ror:8
            v = dpp_ror_add<0x124>(v);         // row_ror:4
            v = dpp_ror_add<0x122>(v);         // row_ror:2
            v = dpp_ror_add<0x121>(v);         // row_ror:1
            acc[j][dd] = v;
        }
    }

    // ---- register-only argmin: in-lane ascending disp index, strict < ----
    float bc = 3.4e38f;
    int   bj = 0x7fffffff;
    if (g < 3) {
        #pragma unroll
        for (int j = 0; j < ND; ++j)
            #pragma unroll
            for (int dd = 0; dd < 3; ++dd) {
                const float cst = acc[j][dd];
                if (cst < bc) { bc = cst; bj = j * ND + d0 + dd; }
            }
    }
    // cross-group min (post-DPP, lanes within a row are identical -> only
    // xor-16 and xor-32 levels needed); lowest index wins ties (jax strict <)
    #pragma unroll
    for (int m = 16; m <= 32; m <<= 1) {
        const float oc = __shfl_xor(bc, m, 64);
        const int   oi = __shfl_xor(bj, m, 64);
        if (oc < bc || (oc == bc && oi < bj)) { bc = oc; bj = oi; }
    }
    const int by = bj / ND;                    // dy + 4
    const int bx = bj % ND;                    // dx + 4

    // ---- gather predicted block from LDS strip (already zero-padded) ----
    #pragma unroll 1
    for (int c = 0; c < Cc; ++c) {
        #pragma unroll
        for (int yy = 0; yy < 4; ++yy) {
            const int y = (g << 2) + yy;
            const float v = ldsA[(c * SH + y + by) * SW + colS + bx];
            predn[(c << 20) + ((Y0 + y) << 10) + X0 + colS] = v;
        }
    }
}

extern "C" void kernel_launch(void* const* d_in, const int* in_sizes, int n_in,
                              void* d_out, int out_size, void* d_ws, size_t ws_size,
                              hipStream_t stream) {
    const float* ref = (const float*)d_in[0];
    const float* tgt = (const float*)d_in[1];
    float* out = (float*)d_out;

    init_kernel<<<dim3((MV_SIZE + 255) / 256), dim3(256), 0, stream>>>(out);

    // zsrc = MV region (zeroed by init_kernel on this stream, never written after)
    hbma_kernel<<<dim3(NWG), dim3(256), 0, stream>>>(ref, tgt, out + MV_SIZE, out);
}